// Round 1
// baseline (4690.829 us; speedup 1.0000x reference)
//
#include <hip/hip_runtime.h>
#include <hip/hip_bf16.h>

// GCN 2-layer forward: x[N,512] @ W1 -> scatter-norm-agg -> +b1,relu
//                      @ W2 -> scatter-norm-agg -> +b2 -> log_softmax
// N=100000, F_IN=512, HID=128, C=40, E=1.6M (+N self loops)

#define F_IN 512
#define HID  128
#define NC   40

// ---------------- degree count ----------------
__global__ void count_deg(const int* __restrict__ dst, int E, unsigned* __restrict__ cnt) {
    int t = blockIdx.x * blockDim.x + threadIdx.x;
    if (t < E) atomicAdd(&cnt[dst[t]], 1u);
}

__global__ void dis_k(const unsigned* __restrict__ cnt, float* __restrict__ dis, int N) {
    int t = blockIdx.x * blockDim.x + threadIdx.x;
    if (t < N) dis[t] = rsqrtf((float)cnt[t] + 1.0f);  // +1 = self loop; always > 0
}

// ---------------- GEMM1: h1[N,128] = x[N,512] @ W1[512,128] ----------------
// block tile 64x128, K-tile 32, 256 threads, each thread 4x8 micro-tile
__global__ __launch_bounds__(256) void gemm1(const float* __restrict__ A,
                                             const float* __restrict__ B,
                                             float* __restrict__ C, int N) {
    __shared__ __align__(16) float As[64][36];   // 32 + 4 pad
    __shared__ __align__(16) float Bs[32][128];
    const int tid = threadIdx.x;
    const int bm = blockIdx.x * 64;
    const int tx = tid & 15;        // col group: 8 cols each
    const int ty = tid >> 4;        // row group: 4 rows each
    float acc[4][8] = {};

    for (int k0 = 0; k0 < F_IN; k0 += 32) {
        // A tile: 64x32 = 512 float4 slots
        #pragma unroll
        for (int i = 0; i < 2; i++) {
            int slot = tid + i * 256;           // 0..511
            int r = slot >> 3;                  // 8 float4 per row
            int c = (slot & 7) << 2;
            float4 v = make_float4(0.f, 0.f, 0.f, 0.f);
            if (bm + r < N)
                v = *(const float4*)(A + (size_t)(bm + r) * F_IN + k0 + c);
            As[r][c + 0] = v.x; As[r][c + 1] = v.y;
            As[r][c + 2] = v.z; As[r][c + 3] = v.w;
        }
        // B tile: 32x128 = 1024 float4 slots
        #pragma unroll
        for (int i = 0; i < 4; i++) {
            int slot = tid + i * 256;           // 0..1023
            int r = slot >> 5;                  // 32 float4 per row
            int c = (slot & 31) << 2;
            *(float4*)&Bs[r][c] = *(const float4*)(B + (size_t)(k0 + r) * HID + c);
        }
        __syncthreads();
        #pragma unroll
        for (int kk = 0; kk < 32; kk++) {
            float a[4], b[8];
            #pragma unroll
            for (int i = 0; i < 4; i++) a[i] = As[ty * 4 + i][kk];
            #pragma unroll
            for (int j = 0; j < 8; j++) b[j] = Bs[kk][tx * 8 + j];
            #pragma unroll
            for (int i = 0; i < 4; i++)
                #pragma unroll
                for (int j = 0; j < 8; j++)
                    acc[i][j] += a[i] * b[j];
        }
        __syncthreads();
    }
    #pragma unroll
    for (int i = 0; i < 4; i++) {
        int r = bm + ty * 4 + i;
        if (r < N) {
            #pragma unroll
            for (int j = 0; j < 8; j += 4) {
                float4 v = make_float4(acc[i][j], acc[i][j+1], acc[i][j+2], acc[i][j+3]);
                *(float4*)(C + (size_t)r * HID + tx * 8 + j) = v;
            }
        }
    }
}

// ---------------- scatter layer 1: 32 threads/edge, float4 each ----------------
__global__ void scatter1(const float* __restrict__ h, const int* __restrict__ src,
                         const int* __restrict__ dst, const float* __restrict__ dis,
                         float* __restrict__ out, int E, int N) {
    int t = blockIdx.x * blockDim.x + threadIdx.x;
    int e = t >> 5;
    if (e >= E + N) return;
    int g = (t & 31) << 2;
    int s, d;
    if (e < E) { s = src[e]; d = dst[e]; } else { s = d = e - E; }
    float nrm = dis[s] * dis[d];
    float4 v = *(const float4*)(h + (size_t)s * HID + g);
    float* o = out + (size_t)d * HID + g;
    atomicAdd(o + 0, v.x * nrm);
    atomicAdd(o + 1, v.y * nrm);
    atomicAdd(o + 2, v.z * nrm);
    atomicAdd(o + 3, v.w * nrm);
}

// ---------------- GEMM2 fused: h2[N,40] = relu(agg1 + b1) @ W2[128,40] ----------------
__global__ __launch_bounds__(256) void gemm2(const float* __restrict__ A,
                                             const float* __restrict__ b1,
                                             const float* __restrict__ W2,
                                             float* __restrict__ C, int N) {
    __shared__ __align__(16) float As[64][132];      // 128 + 4 pad
    __shared__ __align__(16) float Ws[HID * NC];     // 5120 floats, 20 KB
    const int tid = threadIdx.x;
    const int bm = blockIdx.x * 64;
    // W2: 1280 float4 slots
    #pragma unroll
    for (int i = 0; i < 5; i++) {
        int slot = tid + i * 256;
        *(float4*)&Ws[slot * 4] = *(const float4*)(W2 + slot * 4);
    }
    // A tile with bias+relu: 64x128 = 2048 float4 slots
    #pragma unroll
    for (int i = 0; i < 8; i++) {
        int slot = tid + i * 256;
        int r = slot >> 5;
        int c = (slot & 31) << 2;
        float4 v = make_float4(0.f, 0.f, 0.f, 0.f);
        if (bm + r < N) {
            v = *(const float4*)(A + (size_t)(bm + r) * HID + c);
            float4 bb = *(const float4*)(b1 + c);
            v.x = fmaxf(v.x + bb.x, 0.f);
            v.y = fmaxf(v.y + bb.y, 0.f);
            v.z = fmaxf(v.z + bb.z, 0.f);
            v.w = fmaxf(v.w + bb.w, 0.f);
        }
        *(float4*)&As[r][c] = v;
    }
    __syncthreads();
    const int row = tid >> 2;            // 0..63
    const int cg = (tid & 3) * 10;       // 0,10,20,30
    float acc[10] = {};
    for (int k = 0; k < HID; k++) {
        float a = As[row][k];
        #pragma unroll
        for (int j = 0; j < 10; j++)
            acc[j] += a * Ws[k * NC + cg + j];
    }
    int r = bm + row;
    if (r < N) {
        #pragma unroll
        for (int j = 0; j < 10; j++)
            C[(size_t)r * NC + cg + j] = acc[j];
    }
}

// ---------------- scatter layer 2: 8 threads/edge, 5 floats each ----------------
__global__ void scatter2(const float* __restrict__ h, const int* __restrict__ src,
                         const int* __restrict__ dst, const float* __restrict__ dis,
                         float* __restrict__ out, int E, int N) {
    int t = blockIdx.x * blockDim.x + threadIdx.x;
    int e = t >> 3;
    if (e >= E + N) return;
    int g = (t & 7) * 5;
    int s, d;
    if (e < E) { s = src[e]; d = dst[e]; } else { s = d = e - E; }
    float nrm = dis[s] * dis[d];
    const float* hp = h + (size_t)s * NC + g;
    float* o = out + (size_t)d * NC + g;
    #pragma unroll
    for (int k = 0; k < 5; k++)
        atomicAdd(o + k, hp[k] * nrm);
}

// ---------------- log_softmax rows of 40 (+b2), in place ----------------
__global__ void logsoftmax_k(float* __restrict__ out, const float* __restrict__ b2, int N) {
    int r = blockIdx.x * blockDim.x + threadIdx.x;
    if (r >= N) return;
    float* p = out + (size_t)r * NC;
    float v[NC];
    #pragma unroll
    for (int i = 0; i < NC / 4; i++) {
        float4 t = *(const float4*)(p + i * 4);
        float4 bb = *(const float4*)(b2 + i * 4);
        v[i*4+0] = t.x + bb.x; v[i*4+1] = t.y + bb.y;
        v[i*4+2] = t.z + bb.z; v[i*4+3] = t.w + bb.w;
    }
    float mx = -1e30f;
    #pragma unroll
    for (int i = 0; i < NC; i++) mx = fmaxf(mx, v[i]);
    float s = 0.f;
    #pragma unroll
    for (int i = 0; i < NC; i++) s += __expf(v[i] - mx);
    float lse = mx + __logf(s);
    #pragma unroll
    for (int i = 0; i < NC / 4; i++) {
        float4 t = make_float4(v[i*4] - lse, v[i*4+1] - lse, v[i*4+2] - lse, v[i*4+3] - lse);
        *(float4*)(p + i * 4) = t;
    }
}

extern "C" void kernel_launch(void* const* d_in, const int* in_sizes, int n_in,
                              void* d_out, int out_size, void* d_ws, size_t ws_size,
                              hipStream_t stream) {
    const float* x  = (const float*)d_in[0];
    const int*   ei = (const int*)d_in[1];
    const float* W1 = (const float*)d_in[2];
    const float* b1 = (const float*)d_in[3];
    const float* W2 = (const float*)d_in[4];
    const float* b2 = (const float*)d_in[5];
    float* out = (float*)d_out;

    const int N = in_sizes[0] / F_IN;     // 100000
    const int E = in_sizes[1] / 2;        // 1600000
    const int* src = ei;
    const int* dst = ei + E;

    // workspace layout (16B-aligned chunks)
    char* ws = (char*)d_ws;
    unsigned* cnt = (unsigned*)ws;                        // N*4      = 400000
    float* dis    = (float*)(ws + (size_t)N * 4);         // N*4      = 400000
    float* h1     = (float*)(ws + (size_t)N * 8);         // N*128*4  = 51.2MB
    float* agg1   = h1 + (size_t)N * HID;                 // N*128*4  = 51.2MB
    float* h2     = h1;                                   // reuse (h1 dead after scatter1)

    hipMemsetAsync(cnt,  0, (size_t)N * 4, stream);
    hipMemsetAsync(agg1, 0, (size_t)N * HID * 4, stream);
    hipMemsetAsync(out,  0, (size_t)N * NC * 4, stream);

    count_deg<<<(E + 255) / 256, 256, 0, stream>>>(dst, E, cnt);
    dis_k<<<(N + 255) / 256, 256, 0, stream>>>(cnt, dis, N);

    gemm1<<<(N + 63) / 64, 256, 0, stream>>>(x, W1, h1, N);

    const int EN = E + N;
    int g1 = (int)(((size_t)EN * 32 + 255) / 256);
    scatter1<<<g1, 256, 0, stream>>>(h1, src, dst, dis, agg1, E, N);

    gemm2<<<(N + 63) / 64, 256, 0, stream>>>(agg1, b1, W2, h2, N);

    int g2 = (int)(((size_t)EN * 8 + 255) / 256);
    scatter2<<<g2, 256, 0, stream>>>(h2, src, dst, dis, out, E, N);

    logsoftmax_k<<<(N + 255) / 256, 256, 0, stream>>>(out, b2, N);
}

// Round 2
// 837.473 us; speedup vs baseline: 5.6012x; 5.6012x over previous
//
#include <hip/hip_runtime.h>
#include <hip/hip_bf16.h>

// GCN 2-layer forward, CSR pull-aggregation version (no float atomics).
// N=100000, F_IN=512, HID=128, C=40, E=1.6M (+N self loops)

#define F_IN 512
#define HID  128
#define NC   40

// ---------------- degree count (real edges only; +1 self-loop added later) ----
__global__ void count_deg(const int* __restrict__ dst, int E, unsigned* __restrict__ cnt) {
    int t = blockIdx.x * blockDim.x + threadIdx.x;
    if (t < E) atomicAdd(&cnt[dst[t]], 1u);
}

__global__ void dis_k(const unsigned* __restrict__ cnt, float* __restrict__ dis, int N) {
    int t = blockIdx.x * blockDim.x + threadIdx.x;
    if (t < N) dis[t] = rsqrtf((float)cnt[t] + 1.0f);  // +1 = self loop; always > 0
}

// ---------------- prefix sum over deg_total = cnt+1 -> offs (exclusive) -------
__global__ __launch_bounds__(1024) void scan_block(const unsigned* __restrict__ cnt,
                                                   unsigned* __restrict__ offs,
                                                   unsigned* __restrict__ bsums, int N) {
    __shared__ unsigned s[1024];
    int tid = threadIdx.x;
    int i = blockIdx.x * 1024 + tid;
    unsigned v = (i < N) ? cnt[i] + 1u : 0u;
    s[tid] = v;
    __syncthreads();
    #pragma unroll
    for (int d = 1; d < 1024; d <<= 1) {
        unsigned t = (tid >= d) ? s[tid - d] : 0u;
        __syncthreads();
        s[tid] += t;
        __syncthreads();
    }
    if (i < N) offs[i] = s[tid] - v;          // exclusive
    if (tid == 1023) bsums[blockIdx.x] = s[1023];
}

__global__ void scan_bsums(unsigned* __restrict__ bsums, int nb) {
    if (threadIdx.x == 0 && blockIdx.x == 0) {
        unsigned run = 0;
        for (int i = 0; i < nb; i++) {
            unsigned t = bsums[i];
            bsums[i] = run;
            run += t;
        }
    }
}

__global__ __launch_bounds__(1024) void scan_add(unsigned* __restrict__ offs,
                                                 const unsigned* __restrict__ bsums,
                                                 int N, unsigned total) {
    int i = blockIdx.x * 1024 + threadIdx.x;
    if (i < N) offs[i] += bsums[blockIdx.x];
    if (i == 0) offs[N] = total;
}

// ---------------- CSR fill: col[pos] = src for each (edge + self-loop) --------
__global__ void fill_csr(const int* __restrict__ src, const int* __restrict__ dst,
                         const unsigned* __restrict__ offs, unsigned* __restrict__ cursor,
                         int* __restrict__ col, int E, int N) {
    int t = blockIdx.x * blockDim.x + threadIdx.x;
    if (t >= E + N) return;
    int s, d;
    if (t < E) { s = src[t]; d = dst[t]; } else { s = d = t - E; }
    unsigned pos = offs[d] + atomicAdd(&cursor[d], 1u);
    col[pos] = s;
}

// ---------------- GEMM1: h1[N,128] = x[N,512] @ W1[512,128] ----------------
__global__ __launch_bounds__(256) void gemm1(const float* __restrict__ A,
                                             const float* __restrict__ B,
                                             float* __restrict__ C, int N) {
    __shared__ __align__(16) float As[64][36];
    __shared__ __align__(16) float Bs[32][128];
    const int tid = threadIdx.x;
    const int bm = blockIdx.x * 64;
    const int tx = tid & 15;
    const int ty = tid >> 4;
    float acc[4][8] = {};

    for (int k0 = 0; k0 < F_IN; k0 += 32) {
        #pragma unroll
        for (int i = 0; i < 2; i++) {
            int slot = tid + i * 256;
            int r = slot >> 3;
            int c = (slot & 7) << 2;
            float4 v = make_float4(0.f, 0.f, 0.f, 0.f);
            if (bm + r < N)
                v = *(const float4*)(A + (size_t)(bm + r) * F_IN + k0 + c);
            As[r][c + 0] = v.x; As[r][c + 1] = v.y;
            As[r][c + 2] = v.z; As[r][c + 3] = v.w;
        }
        #pragma unroll
        for (int i = 0; i < 4; i++) {
            int slot = tid + i * 256;
            int r = slot >> 5;
            int c = (slot & 31) << 2;
            *(float4*)&Bs[r][c] = *(const float4*)(B + (size_t)(k0 + r) * HID + c);
        }
        __syncthreads();
        #pragma unroll
        for (int kk = 0; kk < 32; kk++) {
            float a[4], b[8];
            #pragma unroll
            for (int i = 0; i < 4; i++) a[i] = As[ty * 4 + i][kk];
            #pragma unroll
            for (int j = 0; j < 8; j++) b[j] = Bs[kk][tx * 8 + j];
            #pragma unroll
            for (int i = 0; i < 4; i++)
                #pragma unroll
                for (int j = 0; j < 8; j++)
                    acc[i][j] += a[i] * b[j];
        }
        __syncthreads();
    }
    #pragma unroll
    for (int i = 0; i < 4; i++) {
        int r = bm + ty * 4 + i;
        if (r < N) {
            #pragma unroll
            for (int j = 0; j < 8; j += 4) {
                float4 v = make_float4(acc[i][j], acc[i][j+1], acc[i][j+2], acc[i][j+3]);
                *(float4*)(C + (size_t)r * HID + tx * 8 + j) = v;
            }
        }
    }
}

// ---------------- pull-aggregation layer 1: 32 lanes/node, float4 each -------
__global__ __launch_bounds__(256) void agg1_k(const float* __restrict__ h,
                                              const int* __restrict__ col,
                                              const unsigned* __restrict__ offs,
                                              const float* __restrict__ dis,
                                              float* __restrict__ out, int N) {
    int node = blockIdx.x * 8 + (threadIdx.x >> 5);
    if (node >= N) return;
    int lane = threadIdx.x & 31;
    unsigned p0 = offs[node], p1 = offs[node + 1];
    float dd = dis[node];
    float4 acc = make_float4(0.f, 0.f, 0.f, 0.f);
    for (unsigned p = p0; p < p1; ++p) {
        int s = col[p];
        float nrm = dis[s] * dd;
        float4 v = *(const float4*)(h + (size_t)s * HID + lane * 4);
        acc.x += v.x * nrm; acc.y += v.y * nrm;
        acc.z += v.z * nrm; acc.w += v.w * nrm;
    }
    *(float4*)(out + (size_t)node * HID + lane * 4) = acc;
}

// ---------------- GEMM2 fused: h2[N,40] = relu(agg1 + b1) @ W2[128,40] -------
__global__ __launch_bounds__(256) void gemm2(const float* __restrict__ A,
                                             const float* __restrict__ b1,
                                             const float* __restrict__ W2,
                                             float* __restrict__ C, int N) {
    __shared__ __align__(16) float As[64][132];
    __shared__ __align__(16) float Ws[HID * NC];
    const int tid = threadIdx.x;
    const int bm = blockIdx.x * 64;
    #pragma unroll
    for (int i = 0; i < 5; i++) {
        int slot = tid + i * 256;
        *(float4*)&Ws[slot * 4] = *(const float4*)(W2 + slot * 4);
    }
    #pragma unroll
    for (int i = 0; i < 8; i++) {
        int slot = tid + i * 256;
        int r = slot >> 5;
        int c = (slot & 31) << 2;
        float4 v = make_float4(0.f, 0.f, 0.f, 0.f);
        if (bm + r < N) {
            v = *(const float4*)(A + (size_t)(bm + r) * HID + c);
            float4 bb = *(const float4*)(b1 + c);
            v.x = fmaxf(v.x + bb.x, 0.f);
            v.y = fmaxf(v.y + bb.y, 0.f);
            v.z = fmaxf(v.z + bb.z, 0.f);
            v.w = fmaxf(v.w + bb.w, 0.f);
        }
        *(float4*)&As[r][c] = v;
    }
    __syncthreads();
    const int row = tid >> 2;
    const int cg = (tid & 3) * 10;
    float acc[10] = {};
    for (int k = 0; k < HID; k++) {
        float a = As[row][k];
        #pragma unroll
        for (int j = 0; j < 10; j++)
            acc[j] += a * Ws[k * NC + cg + j];
    }
    int r = bm + row;
    if (r < N) {
        #pragma unroll
        for (int j = 0; j < 10; j++)
            C[(size_t)r * NC + cg + j] = acc[j];
    }
}

// ---------------- pull-aggregation layer 2: 8 lanes/node, 5 cols (stride 8) --
__global__ __launch_bounds__(256) void agg2_k(const float* __restrict__ h,
                                              const int* __restrict__ col,
                                              const unsigned* __restrict__ offs,
                                              const float* __restrict__ dis,
                                              float* __restrict__ out, int N) {
    int node = blockIdx.x * 32 + (threadIdx.x >> 3);
    if (node >= N) return;
    int lane = threadIdx.x & 7;
    unsigned p0 = offs[node], p1 = offs[node + 1];
    float dd = dis[node];
    float acc[5] = {};
    for (unsigned p = p0; p < p1; ++p) {
        int s = col[p];
        float nrm = dis[s] * dd;
        const float* hp = h + (size_t)s * NC;
        #pragma unroll
        for (int k = 0; k < 5; k++)
            acc[k] += hp[lane + k * 8] * nrm;
    }
    float* o = out + (size_t)node * NC;
    #pragma unroll
    for (int k = 0; k < 5; k++)
        o[lane + k * 8] = acc[k];
}

// ---------------- log_softmax rows of 40 (+b2), in place on out --------------
__global__ void logsoftmax_k(float* __restrict__ out, const float* __restrict__ b2, int N) {
    int r = blockIdx.x * blockDim.x + threadIdx.x;
    if (r >= N) return;
    float* p = out + (size_t)r * NC;
    float v[NC];
    #pragma unroll
    for (int i = 0; i < NC / 4; i++) {
        float4 t = *(const float4*)(p + i * 4);
        float4 bb = *(const float4*)(b2 + i * 4);
        v[i*4+0] = t.x + bb.x; v[i*4+1] = t.y + bb.y;
        v[i*4+2] = t.z + bb.z; v[i*4+3] = t.w + bb.w;
    }
    float mx = -1e30f;
    #pragma unroll
    for (int i = 0; i < NC; i++) mx = fmaxf(mx, v[i]);
    float s = 0.f;
    #pragma unroll
    for (int i = 0; i < NC; i++) s += __expf(v[i] - mx);
    float lse = mx + __logf(s);
    #pragma unroll
    for (int i = 0; i < NC / 4; i++) {
        float4 t = make_float4(v[i*4] - lse, v[i*4+1] - lse, v[i*4+2] - lse, v[i*4+3] - lse);
        *(float4*)(p + i * 4) = t;
    }
}

extern "C" void kernel_launch(void* const* d_in, const int* in_sizes, int n_in,
                              void* d_out, int out_size, void* d_ws, size_t ws_size,
                              hipStream_t stream) {
    const float* x  = (const float*)d_in[0];
    const int*   ei = (const int*)d_in[1];
    const float* W1 = (const float*)d_in[2];
    const float* b1 = (const float*)d_in[3];
    const float* W2 = (const float*)d_in[4];
    const float* b2 = (const float*)d_in[5];
    float* out = (float*)d_out;

    const int N = in_sizes[0] / F_IN;     // 100000
    const int E = in_sizes[1] / 2;        // 1600000
    const int EN = E + N;
    const int* src = ei;
    const int* dst = ei + E;

    // ---- workspace layout (16B aligned) ----
    char* ws = (char*)d_ws;
    size_t o = 0;
    unsigned* cnt  = (unsigned*)(ws + o); o += (size_t)N * 4;        // reused as cursor
    float*    dis  = (float*)   (ws + o); o += (size_t)N * 4;
    unsigned* offs = (unsigned*)(ws + o); o += (size_t)(N + 4) * 4;
    unsigned* bsums= (unsigned*)(ws + o); o += 1024;
    int*      col  = (int*)     (ws + o); o += (size_t)EN * 4;
    o = (o + 15) & ~(size_t)15;
    float*    h1   = (float*)   (ws + o); o += (size_t)N * HID * 4;
    float*    agg1 = (float*)   (ws + o); o += (size_t)N * HID * 4;
    float*    h2   = h1;   // h1 dead after agg1

    const int nb = (N + 1023) / 1024;

    // degree + norm
    hipMemsetAsync(cnt, 0, (size_t)N * 4, stream);
    count_deg<<<(E + 255) / 256, 256, 0, stream>>>(dst, E, cnt);
    dis_k<<<(N + 255) / 256, 256, 0, stream>>>(cnt, dis, N);

    // prefix sum -> offs
    scan_block<<<nb, 1024, 0, stream>>>(cnt, offs, bsums, N);
    scan_bsums<<<1, 64, 0, stream>>>(bsums, nb);
    scan_add<<<nb, 1024, 0, stream>>>(offs, bsums, N, (unsigned)EN);

    // fill CSR (cnt reused as cursor)
    hipMemsetAsync(cnt, 0, (size_t)N * 4, stream);
    fill_csr<<<(EN + 255) / 256, 256, 0, stream>>>(src, dst, offs, cnt, col, E, N);

    // layer 1
    gemm1<<<(N + 63) / 64, 256, 0, stream>>>(x, W1, h1, N);
    agg1_k<<<(N + 7) / 8, 256, 0, stream>>>(h1, col, offs, dis, agg1, N);

    // layer 2
    gemm2<<<(N + 63) / 64, 256, 0, stream>>>(agg1, b1, W2, h2, N);
    agg2_k<<<(N + 31) / 32, 256, 0, stream>>>(h2, col, offs, dis, out, N);

    logsoftmax_k<<<(N + 255) / 256, 256, 0, stream>>>(out, b2, N);
}

// Round 3
// 754.681 us; speedup vs baseline: 6.2156x; 1.1097x over previous
//
#include <hip/hip_runtime.h>
#include <hip/hip_bf16.h>

// GCN 2-layer forward. CSR pull-aggregation + bf16 MFMA for GEMM1.
// N=100000, F_IN=512, HID=128, C=40, E=1.6M (+N self loops)

#define F_IN 512
#define HID  128
#define NC   40

typedef __attribute__((ext_vector_type(8))) short bf16x8;
typedef __attribute__((ext_vector_type(4))) float f32x4v;

__device__ __forceinline__ ushort f2bf(float f) {
    union { float f; unsigned u; } x; x.f = f;
    unsigned r = x.u + 0x7FFFu + ((x.u >> 16) & 1u);   // round-to-nearest-even
    return (ushort)(r >> 16);
}
__device__ __forceinline__ float bf2f(ushort u) {
    return __uint_as_float((unsigned)u << 16);
}

// ---------------- degree count ----------------
__global__ void count_deg(const int* __restrict__ dst, int E, unsigned* __restrict__ cnt) {
    int t = blockIdx.x * blockDim.x + threadIdx.x;
    if (t < E) atomicAdd(&cnt[dst[t]], 1u);
}

__global__ void dis_k(const unsigned* __restrict__ cnt, float* __restrict__ dis, int N) {
    int t = blockIdx.x * blockDim.x + threadIdx.x;
    if (t < N) dis[t] = rsqrtf((float)cnt[t] + 1.0f);  // +1 = self loop
}

// ---------------- prefix sum over deg_total = cnt+1 -> offs (exclusive) -------
__global__ __launch_bounds__(1024) void scan_block(const unsigned* __restrict__ cnt,
                                                   unsigned* __restrict__ offs,
                                                   unsigned* __restrict__ bsums, int N) {
    __shared__ unsigned s[1024];
    int tid = threadIdx.x;
    int i = blockIdx.x * 1024 + tid;
    unsigned v = (i < N) ? cnt[i] + 1u : 0u;
    s[tid] = v;
    __syncthreads();
    #pragma unroll
    for (int d = 1; d < 1024; d <<= 1) {
        unsigned t = (tid >= d) ? s[tid - d] : 0u;
        __syncthreads();
        s[tid] += t;
        __syncthreads();
    }
    if (i < N) offs[i] = s[tid] - v;
    if (tid == 1023) bsums[blockIdx.x] = s[1023];
}

__global__ void scan_bsums(unsigned* __restrict__ bsums, int nb) {
    if (threadIdx.x == 0 && blockIdx.x == 0) {
        unsigned run = 0;
        for (int i = 0; i < nb; i++) { unsigned t = bsums[i]; bsums[i] = run; run += t; }
    }
}

__global__ __launch_bounds__(1024) void scan_add(unsigned* __restrict__ offs,
                                                 const unsigned* __restrict__ bsums,
                                                 int N, unsigned total) {
    int i = blockIdx.x * 1024 + threadIdx.x;
    if (i < N) offs[i] += bsums[blockIdx.x];
    if (i == 0) offs[N] = total;
}

// ---------------- CSR fill ----------------
__global__ void fill_csr(const int* __restrict__ src, const int* __restrict__ dst,
                         const unsigned* __restrict__ offs, unsigned* __restrict__ cursor,
                         int* __restrict__ col, int E, int N) {
    int t = blockIdx.x * blockDim.x + threadIdx.x;
    if (t >= E + N) return;
    int s, d;
    if (t < E) { s = src[t]; d = dst[t]; } else { s = d = t - E; }
    unsigned pos = offs[d] + atomicAdd(&cursor[d], 1u);
    col[pos] = s;
}

// ---------------- W1 pre-pack: fp32[512][128] -> bf16 fragment layout --------
// Bp layout: [s(16)][kb(4)][n(128)][j(8)], k = s*32 + kb*8 + j
__global__ void w1pack(const float* __restrict__ W1, ushort* __restrict__ Bp) {
    int t = blockIdx.x * 256 + threadIdx.x;   // 0..65535
    int j = t & 7, n = (t >> 3) & 127, kb = (t >> 10) & 3, s = t >> 12;
    int k = s * 32 + kb * 8 + j;
    Bp[t] = f2bf(W1[(size_t)k * HID + n]);
}

// ---------------- GEMM1 MFMA: h1_bf16[N,128] = bf16(x[N,512]) @ W1 -----------
// 128x128 block tile, BK=32, 4 waves, each wave 2x8 grid of 16x16x32 MFMAs.
__global__ __launch_bounds__(256) void gemm1_mfma(const float* __restrict__ A,
                                                  const ushort* __restrict__ Bp,
                                                  ushort* __restrict__ C, int N) {
    __shared__ __align__(16) ushort As[128 * 40];   // row stride 40 bf16 (bank-balanced)
    __shared__ __align__(16) ushort Bs[4096];       // [kb][n][8]
    const int tid  = threadIdx.x;
    const int wave = tid >> 6;
    const int lane = tid & 63;
    const int quad = lane >> 4;
    const int mr   = lane & 15;
    const int bm   = blockIdx.x * 128;

    const int r  = tid >> 1;            // staging row 0..127
    const int hh = tid & 1;             // staging k-half
    const bool arow_ok = (bm + r) < N;
    const float* arow = A + (size_t)(bm + r) * F_IN + hh * 16;

    f32x4v acc[2][8];
    #pragma unroll
    for (int i = 0; i < 2; i++)
        #pragma unroll
        for (int t = 0; t < 8; t++)
            acc[i][t] = (f32x4v){0.f, 0.f, 0.f, 0.f};

    for (int s = 0; s < 16; s++) {
        // stage B tile (copy-through, already bf16-packed): 8192 B
        {
            const uint4* srcp = (const uint4*)(Bp + (size_t)s * 4096) + tid * 2;
            uint4 v0 = srcp[0], v1 = srcp[1];
            uint4* dstp = (uint4*)Bs + tid * 2;
            dstp[0] = v0; dstp[1] = v1;
        }
        // stage A tile: 128x32 fp32 -> bf16
        {
            ushort tmp[16];
            if (arow_ok) {
                const float4* ap = (const float4*)(arow + s * 32);
                #pragma unroll
                for (int i = 0; i < 4; i++) {
                    float4 v = ap[i];
                    tmp[i*4+0] = f2bf(v.x); tmp[i*4+1] = f2bf(v.y);
                    tmp[i*4+2] = f2bf(v.z); tmp[i*4+3] = f2bf(v.w);
                }
            } else {
                #pragma unroll
                for (int i = 0; i < 16; i++) tmp[i] = 0;
            }
            uint4* dstp = (uint4*)&As[r * 40 + hh * 16];
            dstp[0] = ((const uint4*)tmp)[0];
            dstp[1] = ((const uint4*)tmp)[1];
        }
        __syncthreads();
        // compute: a frag = A[m=mr][k=quad*8+j]; b frag = B[k=quad*8+j][n=mr]
        bf16x8 a0 = *(const bf16x8*)&As[(wave * 32 + mr) * 40 + quad * 8];
        bf16x8 a1 = *(const bf16x8*)&As[(wave * 32 + 16 + mr) * 40 + quad * 8];
        #pragma unroll
        for (int t = 0; t < 8; t++) {
            bf16x8 b = *(const bf16x8*)&Bs[quad * 1024 + (t * 16 + mr) * 8];
            acc[0][t] = __builtin_amdgcn_mfma_f32_16x16x32_bf16(a0, b, acc[0][t], 0, 0, 0);
            acc[1][t] = __builtin_amdgcn_mfma_f32_16x16x32_bf16(a1, b, acc[1][t], 0, 0, 0);
        }
        __syncthreads();
    }
    // epilogue: C/D layout col=lane&15, row=quad*4+reg
    #pragma unroll
    for (int i = 0; i < 2; i++) {
        int row0 = bm + wave * 32 + i * 16 + quad * 4;
        #pragma unroll
        for (int rr = 0; rr < 4; rr++) {
            int row = row0 + rr;
            if (row < N) {
                #pragma unroll
                for (int t = 0; t < 8; t++)
                    C[(size_t)row * HID + t * 16 + mr] = f2bf(acc[i][t][rr]);
            }
        }
    }
}

// ---------------- pull-aggregation layer 1: 32 lanes/node, 4 bf16 cols each --
__global__ __launch_bounds__(256) void agg1_k(const ushort* __restrict__ h,
                                              const int* __restrict__ col,
                                              const unsigned* __restrict__ offs,
                                              const float* __restrict__ dis,
                                              float* __restrict__ out, int N) {
    int node = blockIdx.x * 8 + (threadIdx.x >> 5);
    if (node >= N) return;
    int lane = threadIdx.x & 31;
    unsigned p0 = offs[node], p1 = offs[node + 1];
    float dd = dis[node];
    float4 acc = make_float4(0.f, 0.f, 0.f, 0.f);
    for (unsigned p = p0; p < p1; ++p) {
        int s = col[p];
        float nrm = dis[s] * dd;
        ushort4 v = *(const ushort4*)(h + (size_t)s * HID + lane * 4);
        acc.x += bf2f(v.x) * nrm; acc.y += bf2f(v.y) * nrm;
        acc.z += bf2f(v.z) * nrm; acc.w += bf2f(v.w) * nrm;
    }
    *(float4*)(out + (size_t)node * HID + lane * 4) = acc;
}

// ---------------- GEMM2 fused: h2[N,40] = relu(agg1 + b1) @ W2[128,40] -------
__global__ __launch_bounds__(256) void gemm2(const float* __restrict__ A,
                                             const float* __restrict__ b1,
                                             const float* __restrict__ W2,
                                             float* __restrict__ C, int N) {
    __shared__ __align__(16) float As[64][132];
    __shared__ __align__(16) float Ws[HID * NC];
    const int tid = threadIdx.x;
    const int bm = blockIdx.x * 64;
    #pragma unroll
    for (int i = 0; i < 5; i++) {
        int slot = tid + i * 256;
        *(float4*)&Ws[slot * 4] = *(const float4*)(W2 + slot * 4);
    }
    #pragma unroll
    for (int i = 0; i < 8; i++) {
        int slot = tid + i * 256;
        int r = slot >> 5;
        int c = (slot & 31) << 2;
        float4 v = make_float4(0.f, 0.f, 0.f, 0.f);
        if (bm + r < N) {
            v = *(const float4*)(A + (size_t)(bm + r) * HID + c);
            float4 bb = *(const float4*)(b1 + c);
            v.x = fmaxf(v.x + bb.x, 0.f);
            v.y = fmaxf(v.y + bb.y, 0.f);
            v.z = fmaxf(v.z + bb.z, 0.f);
            v.w = fmaxf(v.w + bb.w, 0.f);
        }
        *(float4*)&As[r][c] = v;
    }
    __syncthreads();
    const int row = tid >> 2;
    const int cg = (tid & 3) * 10;
    float acc[10] = {};
    for (int k = 0; k < HID; k++) {
        float a = As[row][k];
        #pragma unroll
        for (int j = 0; j < 10; j++)
            acc[j] += a * Ws[k * NC + cg + j];
    }
    int r = bm + row;
    if (r < N) {
        #pragma unroll
        for (int j = 0; j < 10; j++)
            C[(size_t)r * NC + cg + j] = acc[j];
    }
}

// ---------------- pull-aggregation layer 2: 8 lanes/node, 5 cols (stride 8) --
__global__ __launch_bounds__(256) void agg2_k(const float* __restrict__ h,
                                              const int* __restrict__ col,
                                              const unsigned* __restrict__ offs,
                                              const float* __restrict__ dis,
                                              float* __restrict__ out, int N) {
    int node = blockIdx.x * 32 + (threadIdx.x >> 3);
    if (node >= N) return;
    int lane = threadIdx.x & 7;
    unsigned p0 = offs[node], p1 = offs[node + 1];
    float dd = dis[node];
    float acc[5] = {};
    for (unsigned p = p0; p < p1; ++p) {
        int s = col[p];
        float nrm = dis[s] * dd;
        const float* hp = h + (size_t)s * NC;
        #pragma unroll
        for (int k = 0; k < 5; k++)
            acc[k] += hp[lane + k * 8] * nrm;
    }
    float* o = out + (size_t)node * NC;
    #pragma unroll
    for (int k = 0; k < 5; k++)
        o[lane + k * 8] = acc[k];
}

// ---------------- log_softmax rows of 40 (+b2), in place ---------------------
__global__ void logsoftmax_k(float* __restrict__ out, const float* __restrict__ b2, int N) {
    int r = blockIdx.x * blockDim.x + threadIdx.x;
    if (r >= N) return;
    float* p = out + (size_t)r * NC;
    float v[NC];
    #pragma unroll
    for (int i = 0; i < NC / 4; i++) {
        float4 t = *(const float4*)(p + i * 4);
        float4 bb = *(const float4*)(b2 + i * 4);
        v[i*4+0] = t.x + bb.x; v[i*4+1] = t.y + bb.y;
        v[i*4+2] = t.z + bb.z; v[i*4+3] = t.w + bb.w;
    }
    float mx = -1e30f;
    #pragma unroll
    for (int i = 0; i < NC; i++) mx = fmaxf(mx, v[i]);
    float s = 0.f;
    #pragma unroll
    for (int i = 0; i < NC; i++) s += __expf(v[i] - mx);
    float lse = mx + __logf(s);
    #pragma unroll
    for (int i = 0; i < NC / 4; i++) {
        float4 t = make_float4(v[i*4] - lse, v[i*4+1] - lse, v[i*4+2] - lse, v[i*4+3] - lse);
        *(float4*)(p + i * 4) = t;
    }
}

extern "C" void kernel_launch(void* const* d_in, const int* in_sizes, int n_in,
                              void* d_out, int out_size, void* d_ws, size_t ws_size,
                              hipStream_t stream) {
    const float* x  = (const float*)d_in[0];
    const int*   ei = (const int*)d_in[1];
    const float* W1 = (const float*)d_in[2];
    const float* b1 = (const float*)d_in[3];
    const float* W2 = (const float*)d_in[4];
    const float* b2 = (const float*)d_in[5];
    float* out = (float*)d_out;

    const int N = in_sizes[0] / F_IN;     // 100000
    const int E = in_sizes[1] / 2;        // 1600000
    const int EN = E + N;
    const int* src = ei;
    const int* dst = ei + E;

    // ---- workspace layout ----
    char* ws = (char*)d_ws;
    size_t o = 0;
    unsigned* cnt  = (unsigned*)(ws + o); o += (size_t)N * 4;        // reused as cursor
    float*    dis  = (float*)   (ws + o); o += (size_t)N * 4;
    unsigned* offs = (unsigned*)(ws + o); o += (size_t)(N + 4) * 4;
    unsigned* bsums= (unsigned*)(ws + o); o += 1024;
    int*      col  = (int*)     (ws + o); o += (size_t)EN * 4;
    o = (o + 15) & ~(size_t)15;
    ushort*   W1p  = (ushort*)  (ws + o); o += (size_t)F_IN * HID * 2;   // 128 KB
    o = (o + 15) & ~(size_t)15;
    ushort*   h1   = (ushort*)  (ws + o); o += (size_t)N * HID * 2;      // bf16, 25.6 MB
    o = (o + 15) & ~(size_t)15;
    float*    agg1 = (float*)   (ws + o); o += (size_t)N * HID * 4;      // 51.2 MB
    float*    h2   = (float*)h1;   // h1 dead after agg1; 16 MB fits in 25.6 MB

    const int nb = (N + 1023) / 1024;

    // degree + norm
    hipMemsetAsync(cnt, 0, (size_t)N * 4, stream);
    count_deg<<<(E + 255) / 256, 256, 0, stream>>>(dst, E, cnt);
    dis_k<<<(N + 255) / 256, 256, 0, stream>>>(cnt, dis, N);

    // prefix sum -> offs
    scan_block<<<nb, 1024, 0, stream>>>(cnt, offs, bsums, N);
    scan_bsums<<<1, 64, 0, stream>>>(bsums, nb);
    scan_add<<<nb, 1024, 0, stream>>>(offs, bsums, N, (unsigned)EN);

    // fill CSR (cnt reused as cursor)
    hipMemsetAsync(cnt, 0, (size_t)N * 4, stream);
    fill_csr<<<(EN + 255) / 256, 256, 0, stream>>>(src, dst, offs, cnt, col, E, N);

    // layer 1
    w1pack<<<(F_IN * HID) / 256, 256, 0, stream>>>(W1, W1p);
    gemm1_mfma<<<(N + 127) / 128, 256, 0, stream>>>(x, W1p, h1, N);
    agg1_k<<<(N + 7) / 8, 256, 0, stream>>>(h1, col, offs, dis, agg1, N);

    // layer 2
    gemm2<<<(N + 63) / 64, 256, 0, stream>>>(agg1, b1, W2, h2, N);
    agg2_k<<<(N + 31) / 32, 256, 0, stream>>>(h2, col, offs, dis, out, N);

    logsoftmax_k<<<(N + 255) / 256, 256, 0, stream>>>(out, b2, N);
}